// Round 2
// baseline (163.855 us; speedup 1.0000x reference)
//
#include <hip/hip_runtime.h>
#include <hip/hip_bf16.h>

// PE table: out[pos, 2i]   = sin(pos / 10000^(2i/1024))
//           out[pos, 2i+1] = cos(pos / 10000^(2i/1024))
// Output f32 [seq_len, 1024]. Input X is only used for its shape -> never read.
//
// Native-trig path: v_sin/v_cos take REVOLUTIONS (D = sin(S0*2pi)), so fold
// 1/(2*pi) into the exp2 exponent:
//   rev = pos * 2^(-i*K - log2(2*pi)),  K = 2*log2(10000)/D_MODEL.
// fract() before sin/cos is mandatory: rev reaches ~1304, outside v_sin's
// accurate input range; after fract, rev in [0,1).

#define D_MODEL 1024

__global__ __launch_bounds__(256) void PositionalEncoding_31559419691757_kernel(
    float4* __restrict__ out, int n4) {
    const float K = 0.025952563241307522f;  // 2*log2(10000)/D_MODEL
    const float C = 2.6514961294723187f;    // log2(2*pi)

    int idx = blockIdx.x * 256 + threadIdx.x;     // one float4 (2 sin/cos pairs)
    if (idx >= n4) return;

    int row = idx >> 8;          // D_MODEL/4 = 256 float4 per row
    int c4  = idx & 255;
    float fpos = (float)row;
    float i0   = (float)(2 * c4);      // pair index of .x/.y
    float i1   = i0 + 1.0f;            // pair index of .z/.w

    // rev = pos * 2^(-i*K - C)   (C folds the 1/(2*pi) for native sin/cos)
    float e0 = __builtin_amdgcn_exp2f(-(i0 * K) - C);   // v_exp_f32
    float e1 = __builtin_amdgcn_exp2f(-(i1 * K) - C);
    float r0 = __builtin_amdgcn_fractf(fpos * e0);      // v_fract_f32
    float r1 = __builtin_amdgcn_fractf(fpos * e1);

    float4 v;
    v.x = __builtin_amdgcn_sinf(r0);   // v_sin_f32: sin(2*pi*r0)
    v.y = __builtin_amdgcn_cosf(r0);   // v_cos_f32
    v.z = __builtin_amdgcn_sinf(r1);
    v.w = __builtin_amdgcn_cosf(r1);
    out[idx] = v;
}

extern "C" void kernel_launch(void* const* d_in, const int* in_sizes, int n_in,
                              void* d_out, int out_size, void* d_ws, size_t ws_size,
                              hipStream_t stream) {
    (void)d_in; (void)in_sizes; (void)n_in; (void)d_ws; (void)ws_size;
    // out_size = seq_len * D_MODEL floats; seq_len derived from output size.
    int n4 = out_size / 4;                       // float4 elements
    int blocks = (n4 + 255) / 256;
    PositionalEncoding_31559419691757_kernel<<<blocks, 256, 0, stream>>>(
        (float4*)d_out, n4);
}